// Round 1
// baseline (29.907 us; speedup 1.0000x reference)
//
#include <hip/hip_runtime.h>

// Problem constants (from reference): B=2, N=512, M=50, P=2, LQK=LV=9, DQK=DV=32
#define BQ   2
#define NN   512
#define MM   50
#define TDIM 576      // P*L*D = 2*9*32 (both q/k flattened t-dim and v flattened q-dim)
#define T4   144      // TDIM / 4 (float4 count per row)

// Kernel 1: d[b*N+n] = (sum_t q[b,n,t]*k[b,n,t]) / sqrt(TDIM)
// One 64-lane wave per (b,n) row. Vectorized float4 loads, shuffle reduce.
__global__ void __launch_bounds__(64) dotqk_kernel(const float* __restrict__ q,
                                                   const float* __restrict__ k,
                                                   float* __restrict__ d) {
    const int row  = blockIdx.x;      // [0, B*N)
    const int lane = threadIdx.x;     // [0, 64)
    const float4* q4 = (const float4*)(q + (size_t)row * TDIM);
    const float4* k4 = (const float4*)(k + (size_t)row * TDIM);
    float acc = 0.0f;
    for (int i = lane; i < T4; i += 64) {
        float4 a = q4[i];
        float4 b = k4[i];
        acc += a.x * b.x + a.y * b.y + a.z * b.z + a.w * b.w;
    }
    // full-wave (64-lane) butterfly reduce
    for (int off = 32; off > 0; off >>= 1)
        acc += __shfl_down(acc, off, 64);
    if (lane == 0) d[row] = acc * (1.0f / 24.0f);   // 1/sqrt(576)
}

// Kernel 2: out[b,m,n,q] = d[b,n] * w[b,m] * v[b,n,q], written as float4.
__global__ void __launch_bounds__(256) scale_write_kernel(const float* __restrict__ v,
                                                          const float* __restrict__ w,
                                                          const float* __restrict__ d,
                                                          float* __restrict__ out,
                                                          long total4) {
    const long stride = (long)gridDim.x * blockDim.x;
    for (long i = (long)blockIdx.x * blockDim.x + threadIdx.x; i < total4; i += stride) {
        int  q4 = (int)(i % T4);
        long r  = i / T4;
        int  n  = (int)(r % NN); r /= NN;
        int  m  = (int)(r % MM);
        int  b  = (int)(r / MM);
        float s = d[b * NN + n] * w[b * MM + m];
        float4 vv = ((const float4*)v)[(long)(b * NN + n) * T4 + q4];
        float4 o;
        o.x = vv.x * s;
        o.y = vv.y * s;
        o.z = vv.z * s;
        o.w = vv.w * s;
        ((float4*)out)[i] = o;
    }
}

extern "C" void kernel_launch(void* const* d_in, const int* in_sizes, int n_in,
                              void* d_out, int out_size, void* d_ws, size_t ws_size,
                              hipStream_t stream) {
    const float* q      = (const float*)d_in[0];   // [B,N,P,LQK,DQK]
    const float* k      = (const float*)d_in[1];   // [B,N,P,LQK,DQK]
    const float* v      = (const float*)d_in[2];   // [B,N,P,LV,DV]
    // d_in[3] = pos, d_in[4] = grid_u, d_in[6] = theta: unused — the RoPE
    // rotation is orthogonal and cancels in the qf·kf contraction.
    const float* w      = (const float*)d_in[5];   // grid_w [B,M]
    float*       out    = (float*)d_out;           // [B,M,N,P,LV,DV]
    float*       dscal  = (float*)d_ws;            // B*N floats scratch

    dotqk_kernel<<<BQ * NN, 64, 0, stream>>>(q, k, dscal);

    const long total4 = (long)BQ * MM * NN * T4;   // 7,372,800 float4 stores
    scale_write_kernel<<<2048, 256, 0, stream>>>(v, w, dscal, out, total4);
}

// Round 3
// 26.401 us; speedup vs baseline: 1.1328x; 1.1328x over previous
//
#include <hip/hip_runtime.h>

// Problem constants: B=2, N=512, M=50, P=2, L=9, D=32 -> flattened t/q dim = 576
#define BQ     2
#define NN     512
#define MM     50
#define TDIM   576
#define T4     144          // TDIM / 4
#define SPLIT  2            // blocks per (b,n) row; each writes MM/SPLIT m's
#define MSPLIT (MM / SPLIT) // 25

typedef float f4 __attribute__((ext_vector_type(4)));  // native vec for nontemporal store

// Math: ERoPE rotation R is orthogonal and identical for q and k at each
// (b,m,n,pair), so sum_t qr*kr = sum_t q*k (m-independent, no trig needed):
//   out[b,m,n,:] = (q[b,n]·k[b,n] / 24) * grid_w[b,m] * v[b,n,:]
// One block per (b,n,split): compute the dot in-block (redundant across the
// 2 splits, ~4.6 KB read), stage v row in LDS, stream 25 scaled rows out.
__global__ void __launch_bounds__(256) erope_fused_kernel(
        const float* __restrict__ q,
        const float* __restrict__ k,
        const float* __restrict__ v,
        const float* __restrict__ w,
        float* __restrict__ out) {
    const int blk   = blockIdx.x;
    const int split = blk & (SPLIT - 1);
    const int row   = blk >> 1;          // b*NN + n
    const int b     = row >> 9;          // row / NN  (NN = 512)
    const int n     = row & (NN - 1);
    const int t     = threadIdx.x;

    __shared__ f4    vsh[T4];
    __shared__ float red[4];
    __shared__ float dsh;

    // --- q·k dot for this (b,n); threads 0..143 each take one float4 ---
    float acc = 0.0f;
    if (t < T4) {
        const f4 a = ((const f4*)(q + (size_t)row * TDIM))[t];
        const f4 c = ((const f4*)(k + (size_t)row * TDIM))[t];
        vsh[t] = ((const f4*)(v + (size_t)row * TDIM))[t];  // stage v row
        acc = a.x * c.x + a.y * c.y + a.z * c.z + a.w * c.w;
    }
    #pragma unroll
    for (int off = 32; off > 0; off >>= 1)
        acc += __shfl_down(acc, off, 64);
    if ((t & 63) == 0) red[t >> 6] = acc;
    __syncthreads();
    if (t == 0) dsh = (red[0] + red[1] + red[2] + red[3]) * (1.0f / 24.0f);
    __syncthreads();
    const float dval = dsh;

    // --- stream out MSPLIT scaled copies of the v row ---
    const float* wrow = w + b * MM + split * MSPLIT;
    f4* out4 = (f4*)out;
    for (int i = t; i < MSPLIT * T4; i += 256) {
        const int ml = i / T4;           // local m (magic-mul div)
        const int qi = i - ml * T4;
        const int m  = split * MSPLIT + ml;
        const float s = dval * wrow[ml];
        const f4 vv = vsh[qi];
        const f4 o  = vv * s;
        __builtin_nontemporal_store(o, &out4[((size_t)(b * MM + m) * NN + n) * T4 + qi]);
    }
}

extern "C" void kernel_launch(void* const* d_in, const int* in_sizes, int n_in,
                              void* d_out, int out_size, void* d_ws, size_t ws_size,
                              hipStream_t stream) {
    const float* q   = (const float*)d_in[0];   // [B,N,P,LQK,DQK]
    const float* k   = (const float*)d_in[1];
    const float* v   = (const float*)d_in[2];   // [B,N,P,LV,DV]
    // d_in[3]=pos, d_in[4]=grid_u, d_in[6]=theta unused: rotation cancels.
    const float* w   = (const float*)d_in[5];   // grid_w [B,M]
    float*       out = (float*)d_out;           // [B,M,N,P,LV,DV]

    erope_fused_kernel<<<BQ * NN * SPLIT, 256, 0, stream>>>(q, k, v, w, out);
}

// Round 4
// 25.903 us; speedup vs baseline: 1.1546x; 1.0192x over previous
//
#include <hip/hip_runtime.h>

// Problem constants: B=2, N=512, M=50, P=2, L=9, D=32 -> flattened t/q dim = 576
#define BQ     2
#define NN     512
#define MM     50
#define TDIM   576
#define T4     144          // TDIM / 4
#define SPLIT  2            // blocks per (b,n) row; each writes MM/SPLIT m's
#define MSPLIT (MM / SPLIT) // 25

typedef float f4 __attribute__((ext_vector_type(4)));

// Math: ERoPE rotation R is orthogonal and identical for q and k at each
// (b,m,n,pair), so sum_t qr*kr = sum_t q*k (m-independent, no trig needed):
//   out[b,m,n,:] = (q[b,n]·k[b,n] / 24) * grid_w[b,m] * v[b,n,:]
// One block per (b,n,split): compute the dot in-block (redundant across the
// 2 splits, ~4.6 KB read), stage v row in LDS, stream 25 scaled rows out
// with PLAIN stores (nt regressed the write path vs the 6.9 TB/s fill ceiling).
__global__ void __launch_bounds__(256) erope_fused_kernel(
        const float* __restrict__ q,
        const float* __restrict__ k,
        const float* __restrict__ v,
        const float* __restrict__ w,
        float* __restrict__ out) {
    const int blk   = blockIdx.x;
    const int split = blk & (SPLIT - 1);
    const int row   = blk >> 1;          // b*NN + n
    const int b     = row >> 9;          // row / NN  (NN = 512)
    const int n     = row & (NN - 1);
    const int t     = threadIdx.x;

    __shared__ f4    vsh[T4];
    __shared__ float red[4];
    __shared__ float dsh;

    // --- q·k dot for this (b,n); threads 0..143 each take one float4 ---
    float acc = 0.0f;
    if (t < T4) {
        const f4 a = ((const f4*)(q + (size_t)row * TDIM))[t];
        const f4 c = ((const f4*)(k + (size_t)row * TDIM))[t];
        vsh[t] = ((const f4*)(v + (size_t)row * TDIM))[t];  // stage v row
        acc = a.x * c.x + a.y * c.y + a.z * c.z + a.w * c.w;
    }
    #pragma unroll
    for (int off = 32; off > 0; off >>= 1)
        acc += __shfl_down(acc, off, 64);
    if ((t & 63) == 0) red[t >> 6] = acc;
    __syncthreads();
    if (t == 0) dsh = (red[0] + red[1] + red[2] + red[3]) * (1.0f / 24.0f);
    __syncthreads();
    const float dval = dsh;

    // --- stream out MSPLIT scaled copies of the v row (plain coalesced stores) ---
    const float* wrow = w + b * MM + split * MSPLIT;
    // Base of this block's first output row: (b, m0 = split*MSPLIT, n, 0)
    f4* const outbase = (f4*)out
        + ((size_t)(b * MM + split * MSPLIT) * NN + n) * T4;
    const size_t mstride = (size_t)NN * T4;   // float4 stride between m rows

    for (int i = t; i < MSPLIT * T4; i += 256) {
        const int ml = i / T4;               // local m (magic-mul div)
        const int qi = i - ml * T4;
        const float s = dval * wrow[ml];
        const f4 vv = vsh[qi];
        outbase[(size_t)ml * mstride + qi] = vv * s;
    }
}

extern "C" void kernel_launch(void* const* d_in, const int* in_sizes, int n_in,
                              void* d_out, int out_size, void* d_ws, size_t ws_size,
                              hipStream_t stream) {
    const float* q   = (const float*)d_in[0];   // [B,N,P,LQK,DQK]
    const float* k   = (const float*)d_in[1];
    const float* v   = (const float*)d_in[2];   // [B,N,P,LV,DV]
    // d_in[3]=pos, d_in[4]=grid_u, d_in[6]=theta unused: rotation cancels.
    const float* w   = (const float*)d_in[5];   // grid_w [B,M]
    float*       out = (float*)d_out;           // [B,M,N,P,LV,DV]

    erope_fused_kernel<<<BQ * NN * SPLIT, 256, 0, stream>>>(q, k, v, w, out);
}

// Round 5
// 25.368 us; speedup vs baseline: 1.1789x; 1.0211x over previous
//
#include <hip/hip_runtime.h>

// Problem constants: B=2, N=512, M=50, P=2, L=9, D=32 -> flattened t/q dim = 576
#define BQ     2
#define NN     512
#define MM     50
#define TDIM   576
#define T4     144          // float4 per row
#define SPLIT  2            // units per (b,n) row
#define MSPLIT (MM / SPLIT) // 25 m's per unit
#define UNITS  (BQ * NN * SPLIT)  // 2048
#define NWAVES 1024         // 256 blocks x 4 waves; 2 units per wave (grid-stride)

typedef float f4 __attribute__((ext_vector_type(4)));

// Math: the ERoPE rotation is orthogonal and identical for q,k at each
// (b,m,n,pair), so sum_t qr*kr = sum_t q*k (m-independent, trig-free):
//   out[b,m,n,:] = (q[b,n]·k[b,n] / 24) * grid_w[b,m] * v[b,n,:]
//
// Structure: one 64-lane WAVE per unit (b,n,split) — no LDS, no barriers.
// v row lives in registers (144 float4 = 2.25/lane). Waves grid-stride over
// 2 units each so the unit-2 load/dot phase overlaps other waves' stores
// (the all-blocks-dot-at-t0 serialization cost of the block version).
__global__ void __launch_bounds__(256) erope_wave_kernel(
        const float* __restrict__ q,
        const float* __restrict__ k,
        const float* __restrict__ v,
        const float* __restrict__ w,
        float* __restrict__ out) {
    const int gwave = blockIdx.x * 4 + (threadIdx.x >> 6);  // 0..NWAVES-1
    const int lane  = threadIdx.x & 63;

    for (int u = gwave; u < UNITS; u += NWAVES) {
        const int split = u & (SPLIT - 1);
        const int row   = u >> 1;            // b*NN + n
        const int b     = row >> 9;          // NN = 512
        const int n     = row & (NN - 1);

        const f4* q4 = (const f4*)(q + (size_t)row * TDIM);
        const f4* k4 = (const f4*)(k + (size_t)row * TDIM);
        const f4* v4 = (const f4*)(v + (size_t)row * TDIM);

        // --- per-wave q·k dot + v row into registers ---
        f4 a0 = q4[lane],      c0 = k4[lane];
        f4 a1 = q4[lane + 64], c1 = k4[lane + 64];
        f4 v0 = v4[lane],      v1 = v4[lane + 64];
        f4 v2 = {0.f, 0.f, 0.f, 0.f};
        float acc = a0.x*c0.x + a0.y*c0.y + a0.z*c0.z + a0.w*c0.w
                  + a1.x*c1.x + a1.y*c1.y + a1.z*c1.z + a1.w*c1.w;
        if (lane < 16) {                     // tail: 144 = 2*64 + 16
            f4 a2 = q4[lane + 128], c2 = k4[lane + 128];
            v2 = v4[lane + 128];
            acc += a2.x*c2.x + a2.y*c2.y + a2.z*c2.z + a2.w*c2.w;
        }
        #pragma unroll
        for (int off = 32; off > 0; off >>= 1)
            acc += __shfl_xor(acc, off, 64);
        const float dval = acc * (1.0f / 24.0f);   // 1/sqrt(576)

        // --- stream 25 scaled copies of the v row ---
        const float* wp = w + b * MM + split * MSPLIT;
        f4* ob = (f4*)out
               + ((size_t)(b * MM + split * MSPLIT) * NN + n) * T4 + lane;
        const size_t mstride = (size_t)NN * T4;    // float4 stride between m's

        #pragma unroll
        for (int ml = 0; ml < MSPLIT; ++ml) {
            const float s = dval * wp[ml];
            f4* p = ob + (size_t)ml * mstride;
            p[0]   = v0 * s;
            p[64]  = v1 * s;
            if (lane < 16) p[128] = v2 * s;
        }
    }
}

extern "C" void kernel_launch(void* const* d_in, const int* in_sizes, int n_in,
                              void* d_out, int out_size, void* d_ws, size_t ws_size,
                              hipStream_t stream) {
    const float* q   = (const float*)d_in[0];   // [B,N,P,LQK,DQK]
    const float* k   = (const float*)d_in[1];
    const float* v   = (const float*)d_in[2];   // [B,N,P,LV,DV]
    // d_in[3]=pos, d_in[4]=grid_u, d_in[6]=theta unused: rotation cancels.
    const float* w   = (const float*)d_in[5];   // grid_w [B,M]
    float*       out = (float*)d_out;           // [B,M,N,P,LV,DV]

    erope_wave_kernel<<<NWAVES / 4, 256, 0, stream>>>(q, k, v, w, out);
}

// Round 6
// 25.010 us; speedup vs baseline: 1.1958x; 1.0143x over previous
//
#include <hip/hip_runtime.h>

// Problem constants: B=2, N=512, M=50, P=2, L=9, D=32 -> flattened t/q dim = 576
#define BQ     2
#define NN     512
#define MM     50
#define TDIM   576
#define T4     144          // float4 per row
#define SPLIT  2            // units per (b,n) row
#define MSPLIT (MM / SPLIT) // 25 m's per unit
#define UNITS  (BQ * NN * SPLIT)  // 2048 units = 2048 waves, one each

typedef float f4 __attribute__((ext_vector_type(4)));

// Math: the ERoPE rotation is orthogonal and identical for q,k at each
// (b,m,n,pair), so sum_t qr*kr = sum_t q*k (m-independent, trig-free):
//   out[b,m,n,:] = (q[b,n]·k[b,n] / 24) * grid_w[b,m] * v[b,n,:]
//
// One 64-lane wave per unit (b,n,split); 2048 waves total (8/CU). No LDS,
// no barriers, no grid-stride: exactly ONE load+dot phase at t=0, then a
// pure store stream (the grid-stride version re-entered a lockstep load
// phase mid-kernel, bubbling the store pipe).
__global__ void __launch_bounds__(256) erope_wave_kernel(
        const float* __restrict__ q,
        const float* __restrict__ k,
        const float* __restrict__ v,
        const float* __restrict__ w,
        float* __restrict__ out) {
    const int u    = blockIdx.x * 4 + (threadIdx.x >> 6);  // 0..UNITS-1
    const int lane = threadIdx.x & 63;

    const int split = u & (SPLIT - 1);
    const int row   = u >> 1;            // b*NN + n
    const int b     = row >> 9;          // NN = 512
    const int n     = row & (NN - 1);

    const f4* q4 = (const f4*)(q + (size_t)row * TDIM);
    const f4* k4 = (const f4*)(k + (size_t)row * TDIM);
    const f4* v4 = (const f4*)(v + (size_t)row * TDIM);

    // --- per-wave q·k dot + v row into registers (144 = 2*64 + 16) ---
    f4 a0 = q4[lane],      c0 = k4[lane];
    f4 a1 = q4[lane + 64], c1 = k4[lane + 64];
    f4 v0 = v4[lane],      v1 = v4[lane + 64];
    f4 v2 = {0.f, 0.f, 0.f, 0.f};
    float acc = a0.x*c0.x + a0.y*c0.y + a0.z*c0.z + a0.w*c0.w
              + a1.x*c1.x + a1.y*c1.y + a1.z*c1.z + a1.w*c1.w;
    if (lane < 16) {
        f4 a2 = q4[lane + 128], c2 = k4[lane + 128];
        v2 = v4[lane + 128];
        acc += a2.x*c2.x + a2.y*c2.y + a2.z*c2.z + a2.w*c2.w;
    }
    #pragma unroll
    for (int off = 32; off > 0; off >>= 1)
        acc += __shfl_xor(acc, off, 64);
    const float dval = acc * (1.0f / 24.0f);   // 1/sqrt(576)

    // --- stream 25 scaled copies of the v row ---
    const float* wp = w + b * MM + split * MSPLIT;
    f4* ob = (f4*)out
           + ((size_t)(b * MM + split * MSPLIT) * NN + n) * T4 + lane;
    const size_t mstride = (size_t)NN * T4;    // float4 stride between m's

    #pragma unroll
    for (int ml = 0; ml < MSPLIT; ++ml) {
        const float s = dval * wp[ml];
        f4* p = ob + (size_t)ml * mstride;
        p[0]   = v0 * s;
        p[64]  = v1 * s;
        if (lane < 16) p[128] = v2 * s;
    }
}

extern "C" void kernel_launch(void* const* d_in, const int* in_sizes, int n_in,
                              void* d_out, int out_size, void* d_ws, size_t ws_size,
                              hipStream_t stream) {
    const float* q   = (const float*)d_in[0];   // [B,N,P,LQK,DQK]
    const float* k   = (const float*)d_in[1];
    const float* v   = (const float*)d_in[2];   // [B,N,P,LV,DV]
    // d_in[3]=pos, d_in[4]=grid_u, d_in[6]=theta unused: rotation cancels.
    const float* w   = (const float*)d_in[5];   // grid_w [B,M]
    float*       out = (float*)d_out;           // [B,M,N,P,LV,DV]

    erope_wave_kernel<<<UNITS / 4, 256, 0, stream>>>(q, k, v, w, out);
}